// Round 1
// 231.667 us; speedup vs baseline: 1.0799x; 1.0799x over previous
//
#include <hip/hip_runtime.h>

#define IMG_H 224
#define IMG_W 224
#define HW (IMG_H * IMG_W)
#define NUM_ROWS 159
#define NUM_COLS 1024
#define BATCH 128
#define OVF_CAP 4096
#define MAXC 12    // static prefetch covers 768; dynamic tail handles any excess
#define NBUCK 512  // counting-sort buckets; bucket = floor(val*512), exact & monotone
#define NHWORDS (NBUCK / 2)  // u32 words, 2 packed u16 counters each

// Exact integer sqrt (v <= ~25k here, f32 sqrt + fixup loops).
__device__ __forceinline__ int isqrt_i(int v) {
    int u = (int)sqrtf((float)v);
    while (u > 0 && u * u > v) --u;
    while ((u + 1) * (u + 1) <= v) ++u;
    return u;
}

// Compiler + wave-order fence for wave-private LDS (DS pipe is in-order per
// wave; the asm stops compiler reordering and drains lgkm before reuse).
__device__ __forceinline__ void lds_fence() {
    asm volatile("s_waitcnt lgkmcnt(0)" ::: "memory");
}

// ---------------------------------------------------------------------------
// Analytic ring build (verified R3-R5). round(sqrt(dx^2+dy^2)) == d
//   <=>  Araw <= dx^2+dy^2 <= d^2+d,  Araw = (d==0 ? 0 : d^2-d+1)
// ---------------------------------------------------------------------------
__global__ __launch_bounds__(256) void build_rings(int* __restrict__ ring_pix,
                                                   int* __restrict__ ring_cnt,
                                                   int* __restrict__ ovf_cnt) {
    const int d = blockIdx.x;
    const int tid = threadIdx.x;  // y = tid for tid < 224
    __shared__ int scnt[256];
    if (d == 0 && tid == 0) ovf_cnt[0] = 0;

    int cnt = 0;
    int x0l = 0, x1l = -1, x0r = 0, x1r = -1;
    if (tid < IMG_H) {
        const int dy = tid - 112;
        const int Araw = (d == 0) ? 0 : (d * d - d + 1);
        int A = Araw - dy * dy;
        if (A < 0) A = 0;
        const int B = d * d + d - dy * dy;
        if (B >= 0) {
            const int hi = isqrt_i(B);
            int lo = isqrt_i(A);
            if (lo * lo < A) ++lo;
            if (lo <= hi) {
                if (lo == 0) {
                    x0l = 112 - min(hi, 112);
                    x1l = 112 + min(hi, 111);
                } else {
                    x0l = 112 - min(hi, 112);
                    x1l = 112 - lo;
                    x0r = 112 + lo;
                    x1r = 112 + min(hi, 111);
                }
                cnt = max(0, x1l - x0l + 1) + max(0, x1r - x0r + 1);
            }
        }
    }
    scnt[tid] = cnt;
    __syncthreads();
    for (int off = 1; off < 256; off <<= 1) {
        const int mine = scnt[tid];
        const int add = (tid >= off) ? scnt[tid - off] : 0;
        __syncthreads();
        scnt[tid] = mine + add;
        __syncthreads();
    }
    if (tid < IMG_H && cnt > 0) {
        int j = d * NUM_COLS + (scnt[tid] - cnt);
        const int rowbase = tid * IMG_W;
        for (int x = x0l; x <= x1l; ++x) ring_pix[j++] = rowbase + x;
        for (int x = x0r; x <= x1r; ++x) ring_pix[j++] = rowbase + x;
    }
    if (tid == 255) ring_cnt[d] = scnt[255];
}

// ---------------------------------------------------------------------------
// Gather + LDS counting sort (replaces the register bitonic sort; R7).
//
// Rationale: bitonic cross-lane passes are fixed at 21 and each moves all E
// u64 elements through ds_bpermute (42*E DS instrs + ~450*E VALU per ring) —
// rocprof showed this VALU/DS work, not memory, dominates (VALUBusy 34% at
// 10% HBM). Counting sort is O(k): bucket = floor(val*NBUCK) (x*512 is an
// exact exponent shift => exact floor, monotone in the float value and hence
// in the uint key), histogram in packed u16 halfwords, wave prefix-scan,
// atomic-cursor scatter of the full key, then odd-even transposition cleanup
// over adjacent slots until no swaps. Buckets are monotone in the key, so a
// swap can only happen INSIDE a same-bucket run (expected length 1-3); the
// fixpoint loop makes the result exact regardless of LDS-atomic lane order.
//
// Key = prand_bits(32) << 16 | pixel(16): within a ring, pixel ascending ==
// column ascending (row-major ring order), so equal prand f32 bits tie-break
// exactly like jax's stable argsort (verified R4).
// Returns k (#selected). If k > CAP nothing past the histogram ran; caller
// defers to the overflow kernel (CAP=1024 covers any ring, max n ~703).
// ---------------------------------------------------------------------------
template <int CAP>
__device__ int gather_count_sort(
    int b, int d, int lane,
    const float* __restrict__ img, const float* __restrict__ mask,
    const float* __restrict__ prand, float* __restrict__ out,
    const int* __restrict__ ring_pix, int n,
    unsigned long long* __restrict__ srt, unsigned* __restrict__ hist,
    unsigned short* __restrict__ dstpix) {
    const float* imgb  = img  + (size_t)b * HW;
    const float* maskb = mask + (size_t)b * HW;
    const float* prb   = prand + ((size_t)b * NUM_ROWS + d) * NUM_COLS;
    float* outb = out + (size_t)b * HW;
    const unsigned long long ltmask = (1ull << lane) - 1ull;
    const int* rp = ring_pix + d * NUM_COLS;

    // zero histogram (wave-private region)
#pragma unroll
    for (int t = 0; t < NHWORDS / 64; ++t) hist[t * 64 + lane] = 0;

    // Software-pipelined loads (R6 pattern): all ring_pix chunks, then all
    // img/mask/prand loads back-to-back. Clamped dup loads stay coalesced.
    int p[MAXC];
    float v[MAXC], m[MAXC];
    unsigned kb[MAXC];
#pragma unroll
    for (int c = 0; c < MAXC; ++c) p[c] = rp[min(c * 64 + lane, n - 1)];
#pragma unroll
    for (int c = 0; c < MAXC; ++c) v[c] = imgb[p[c]];
#pragma unroll
    for (int c = 0; c < MAXC; ++c) m[c] = maskb[p[c]];
#pragma unroll
    for (int c = 0; c < MAXC; ++c)
        kb[c] = __float_as_uint(prb[min(c * 64 + lane, n - 1)]);  // clamp to n-1: dup line, not 768-col stream

    lds_fence();  // hist zeroing ordered before atomics (compiler fence)

    // Pass A: pass-through writes, compact index via ballot, histogram.
    int base = 0;
#pragma unroll
    for (int c = 0; c < MAXC; ++c) {
        const int i = c * 64 + lane;
        const bool active = (i < n);
        const bool sel = active && (m[c] < 0.5f);
        if (active && !sel) outb[p[c]] = v[c];  // pass-through
        const unsigned long long ball = __ballot(sel);
        if (sel) {
            const int j = base + __popcll(ball & ltmask);
            if (j < CAP) dstpix[j] = (unsigned short)p[c];
            const int bk = (int)(__uint_as_float(kb[c]) * (float)NBUCK);
            atomicAdd(&hist[bk >> 1], 1u << ((bk & 1) * 16));
        }
        base += __popcll(ball);
    }
    // Dynamic tail (defensive; taken only if some ring has n > 64*MAXC).
    for (int c0 = MAXC * 64; c0 < n; c0 += 64) {
        const int i = c0 + lane;
        bool sel = false;
        int pp = 0;
        unsigned kk = 0;
        if (i < n) {
            pp = rp[i];
            const float vv = imgb[pp];
            kk = __float_as_uint(prb[i]);
            sel = (maskb[pp] < 0.5f);
            if (!sel) outb[pp] = vv;
        }
        const unsigned long long ball = __ballot(sel);
        if (sel) {
            const int j = base + __popcll(ball & ltmask);
            if (j < CAP) dstpix[j] = (unsigned short)pp;
            const int bk = (int)(__uint_as_float(kk) * (float)NBUCK);
            atomicAdd(&hist[bk >> 1], 1u << ((bk & 1) * 16));
        }
        base += __popcll(ball);
    }
    const int k = base;
    if (k > CAP) return k;  // deep binomial tail: caller defers (main kernel only)

    lds_fence();  // histogram visible

    // Exclusive prefix over NBUCK buckets (packed halfword pairs):
    // serial per-lane over WPL consecutive words, then wave scan of totals.
    constexpr int WPL = NHWORDS / 64;
    unsigned neww[WPL];
    unsigned run = 0;
#pragma unroll
    for (int t = 0; t < WPL; ++t) {
        const unsigned w = hist[lane * WPL + t];
        const unsigned c0 = w & 0xffffu;
        neww[t] = run | ((run + c0) << 16);
        run += c0 + (w >> 16);
    }
    const unsigned own = run;
#pragma unroll
    for (int off = 1; off < 64; off <<= 1) {
        const unsigned o = __shfl_up(run, off, 64);
        if (lane >= off) run += o;
    }
    const unsigned basex = run - own;
#pragma unroll
    for (int t = 0; t < WPL; ++t)
        hist[lane * WPL + t] = neww[t] + (basex | (basex << 16));

    lds_fence();  // cursors visible

    // Pass B: atomic-cursor scatter of full keys into bucket-sorted order.
#pragma unroll
    for (int c = 0; c < MAXC; ++c) {
        const int i = c * 64 + lane;
        if (i < n && m[c] < 0.5f) {
            const int bk = (int)(__uint_as_float(kb[c]) * (float)NBUCK);
            const unsigned sh = (unsigned)((bk & 1) * 16);
            const unsigned old = atomicAdd(&hist[bk >> 1], 1u << sh);
            const int pos = (int)((old >> sh) & 0xffffu);
            srt[pos] = ((unsigned long long)kb[c] << 16) | (unsigned)p[c];
        }
    }
    for (int c0 = MAXC * 64; c0 < n; c0 += 64) {  // tail reload (cold)
        const int i = c0 + lane;
        if (i < n) {
            const int pp = rp[i];
            if (maskb[pp] < 0.5f) {
                const unsigned kk = __float_as_uint(prb[i]);
                const int bk = (int)(__uint_as_float(kk) * (float)NBUCK);
                const unsigned sh = (unsigned)((bk & 1) * 16);
                const unsigned old = atomicAdd(&hist[bk >> 1], 1u << sh);
                const int pos = (int)((old >> sh) & 0xffffu);
                srt[pos] = ((unsigned long long)kk << 16) | (unsigned)pp;
            }
        }
    }

    lds_fence();  // scatter complete

    // Cleanup: odd-even transposition on full keys until a clean round.
    // Cross-bucket adjacent pairs are already ordered, so this only sorts
    // the (tiny) same-bucket runs left arbitrary by atomic lane order.
    while (true) {
        bool sw = false;
        for (int i0 = 2 * lane; i0 + 1 < k; i0 += 128) {  // even pairs
            const unsigned long long a = srt[i0], bb = srt[i0 + 1];
            if (a > bb) { srt[i0] = bb; srt[i0 + 1] = a; sw = true; }
        }
        lds_fence();
        for (int i0 = 2 * lane + 1; i0 + 1 < k; i0 += 128) {  // odd pairs
            const unsigned long long a = srt[i0], bb = srt[i0 + 1];
            if (a > bb) { srt[i0] = bb; srt[i0 + 1] = a; sw = true; }
        }
        lds_fence();
        if (__ballot(sw) == 0) break;
    }
    return k;
}

// Epilogue: rank r's source pixel is srt[r] low 16 bits; its destination is
// the r-th occupied slot's pixel (dstpix[r], ring order => arc-contiguous
// coalesced writes; the img gather is random within the L2-hot ring).
__device__ __forceinline__ void scatter_out(
    const unsigned long long* __restrict__ srt,
    const unsigned short* __restrict__ dstpix, int k, int lane,
    const float* __restrict__ imgb, float* __restrict__ outb) {
    const unsigned short* s16 = (const unsigned short*)srt;  // low halfword of key j at 4*j
    for (int j = lane; j < k; j += 64) {
        const int psrc = s16[4 * j];
        const int pdst = dstpix[j];
        outb[pdst] = imgb[psrc];
    }
}

// ---------------------------------------------------------------------------
// Main: one WAVE per (batch, ring); 4 waves/block; XCD-swizzled (16 whole
// images per XCD). No block barriers — waves fully independent.
// LDS: 4 x (512 u64 srt + 256 u32 hist + 512 u16 dstpix) = 24 KB -> 6 blk/CU.
// ---------------------------------------------------------------------------
__global__ __launch_bounds__(256) void radial_shuffle(
    const float* __restrict__ img, const float* __restrict__ mask,
    const float* __restrict__ prand, float* __restrict__ out,
    const int* __restrict__ ring_pix, const int* __restrict__ ring_cnt,
    int* __restrict__ ovf_cnt, int* __restrict__ ovf_list) {
    const int tid = threadIdx.x;
    const int wid = tid >> 6;
    const int lane = tid & 63;
    const int xcd = blockIdx.x & 7;
    const int g = (blockIdx.x >> 3) * 4 + wid;  // 0..2543 within XCD
    const int b = xcd * (BATCH / 8) + g / NUM_ROWS;
    const int d = g % NUM_ROWS;
    const int n = ring_cnt[d];

    __shared__ unsigned long long srt_s[4][512];  // 16 KB
    __shared__ unsigned hist_s[4][NHWORDS];       // 4 KB
    __shared__ unsigned short dp_s[4][512];       // 4 KB

    const int k = gather_count_sort<512>(b, d, lane, img, mask, prand, out,
                                         ring_pix, n, srt_s[wid], hist_s[wid],
                                         dp_s[wid]);

    if (k > 512) {
        // deep binomial tail: defer to overflow kernel
        if (lane == 0) {
            const int idx = atomicAdd(ovf_cnt, 1);
            if (idx < OVF_CAP) ovf_list[idx] = b * NUM_ROWS + d;
        }
    } else if (k > 0) {
        scatter_out(srt_s[wid], dp_s[wid], k, lane, img + (size_t)b * HW,
                    out + (size_t)b * HW);
    }
}

// Cold path: rings with k > 512 (capacity 1024 >= any ring, rings <= 1024).
__global__ __launch_bounds__(64) void overflow_sort(
    const float* __restrict__ img, const float* __restrict__ mask,
    const float* __restrict__ prand, float* __restrict__ out,
    const int* __restrict__ ring_pix, const int* __restrict__ ring_cnt,
    const int* __restrict__ ovf_cnt, const int* __restrict__ ovf_list) {
    __shared__ unsigned long long srt[1024];   // 8 KB
    __shared__ unsigned hist[NHWORDS];         // 1 KB
    __shared__ unsigned short dstpix[1024];    // 2 KB
    const int m = min(*ovf_cnt, OVF_CAP);
    const int lane = threadIdx.x;
    for (int t = blockIdx.x; t < m; t += gridDim.x) {
        const int bd = ovf_list[t];
        const int b = bd / NUM_ROWS;
        const int d = bd % NUM_ROWS;
        const int k = gather_count_sort<1024>(b, d, lane, img, mask, prand,
                                              out, ring_pix, ring_cnt[d], srt,
                                              hist, dstpix);
        scatter_out(srt, dstpix, k, lane, img + (size_t)b * HW,
                    out + (size_t)b * HW);
        __syncthreads();  // before LDS reuse (single wave: cheap)
    }
}

extern "C" void kernel_launch(void* const* d_in, const int* in_sizes, int n_in,
                              void* d_out, int out_size, void* d_ws, size_t ws_size,
                              hipStream_t stream) {
    const float* img   = (const float*)d_in[0];  // (128,224,224,1) f32
    const float* mask  = (const float*)d_in[1];  // (128,224,224)   f32
    const float* prand = (const float*)d_in[2];  // (128,159,1024)  f32
    float* out = (float*)d_out;                  // (128,224,224,1) f32

    int* ring_pix = (int*)d_ws;                       // 159*1024 ints
    int* ring_cnt = ring_pix + NUM_ROWS * NUM_COLS;   // 159 ints
    int* ovf_cnt  = ring_cnt + NUM_ROWS;              // 1 int
    int* ovf_list = ovf_cnt + 1;                      // OVF_CAP ints

    hipLaunchKernelGGL(build_rings, dim3(NUM_ROWS), dim3(256), 0, stream,
                       ring_pix, ring_cnt, ovf_cnt);
    hipLaunchKernelGGL(radial_shuffle, dim3(BATCH * NUM_ROWS / 4), dim3(256), 0,
                       stream, img, mask, prand, out, ring_pix, ring_cnt,
                       ovf_cnt, ovf_list);
    hipLaunchKernelGGL(overflow_sort, dim3(32), dim3(64), 0, stream,
                       img, mask, prand, out, ring_pix, ring_cnt,
                       ovf_cnt, ovf_list);
}

// Round 2
// 201.039 us; speedup vs baseline: 1.2444x; 1.1524x over previous
//
#include <hip/hip_runtime.h>

#define IMG_H 224
#define IMG_W 224
#define HW (IMG_H * IMG_W)   // 50176 (divisible by 8)
#define HWB (HW / 8)         // 6272 selbit bytes per image
#define NUM_ROWS 159
#define NUM_COLS 1024
#define BATCH 128
#define OVF_CAP 4096
#define MAXC 12              // static prefetch covers 768 >= max ring (~703); tail defensive
#define NBUCK 512            // counting-sort buckets; bucket = floor(val*512), exact & monotone
#define NHWORDS (NBUCK / 2)  // u32 words, 2 packed u16 counters each
#define WPL (NHWORDS / 64)   // 4 hist words (8 buckets) owned per lane

// Exact integer sqrt (v <= ~25k here, f32 sqrt + fixup loops).
__device__ __forceinline__ int isqrt_i(int v) {
    int u = (int)sqrtf((float)v);
    while (u > 0 && u * u > v) --u;
    while ((u + 1) * (u + 1) <= v) ++u;
    return u;
}

// Compiler + wave-order fence for wave-private LDS (DS pipe is in-order per
// wave; the asm stops compiler reordering and drains lgkm before reuse).
__device__ __forceinline__ void lds_fence() {
    asm volatile("s_waitcnt lgkmcnt(0)" ::: "memory");
}

// ---------------------------------------------------------------------------
// Analytic ring build (verified R3-R5). round(sqrt(dx^2+dy^2)) == d
//   <=>  Araw <= dx^2+dy^2 <= d^2+d,  Araw = (d==0 ? 0 : d^2-d+1)
// ring_pix is u16 now (pixel < 50176 fits): halves footprint -> L2-hot.
// ---------------------------------------------------------------------------
__global__ __launch_bounds__(256) void build_rings(unsigned short* __restrict__ ring_pix,
                                                   int* __restrict__ ring_cnt,
                                                   int* __restrict__ ovf_cnt) {
    const int d = blockIdx.x;
    const int tid = threadIdx.x;  // y = tid for tid < 224
    __shared__ int scnt[256];
    if (d == 0 && tid == 0) ovf_cnt[0] = 0;

    int cnt = 0;
    int x0l = 0, x1l = -1, x0r = 0, x1r = -1;
    if (tid < IMG_H) {
        const int dy = tid - 112;
        const int Araw = (d == 0) ? 0 : (d * d - d + 1);
        int A = Araw - dy * dy;
        if (A < 0) A = 0;
        const int B = d * d + d - dy * dy;
        if (B >= 0) {
            const int hi = isqrt_i(B);
            int lo = isqrt_i(A);
            if (lo * lo < A) ++lo;
            if (lo <= hi) {
                if (lo == 0) {
                    x0l = 112 - min(hi, 112);
                    x1l = 112 + min(hi, 111);
                } else {
                    x0l = 112 - min(hi, 112);
                    x1l = 112 - lo;
                    x0r = 112 + lo;
                    x1r = 112 + min(hi, 111);
                }
                cnt = max(0, x1l - x0l + 1) + max(0, x1r - x0r + 1);
            }
        }
    }
    scnt[tid] = cnt;
    __syncthreads();
    for (int off = 1; off < 256; off <<= 1) {
        const int mine = scnt[tid];
        const int add = (tid >= off) ? scnt[tid - off] : 0;
        __syncthreads();
        scnt[tid] = mine + add;
        __syncthreads();
    }
    if (tid < IMG_H && cnt > 0) {
        int j = d * NUM_COLS + (scnt[tid] - cnt);
        const int rowbase = tid * IMG_W;
        for (int x = x0l; x <= x1l; ++x) ring_pix[j++] = (unsigned short)(rowbase + x);
        for (int x = x0r; x <= x1r; ++x) ring_pix[j++] = (unsigned short)(rowbase + x);
    }
    if (tid == 255) ring_cnt[d] = scnt[255];
}

// ---------------------------------------------------------------------------
// Coalesced pre-pass (R8): out = img for ALL pixels (the old scattered
// pass-through), and pack (mask < 0.5) into 1 bit/pixel. The selbit array is
// 800 KB total (~100 KB per XCD slice) -> L2-resident for the ring kernel.
// Removes ~60% of the ring kernel's scattered VMEM transactions.
// ---------------------------------------------------------------------------
__global__ __launch_bounds__(256) void copy_sel(const float4* __restrict__ img4,
                                                const float4* __restrict__ mask4,
                                                float4* __restrict__ out4,
                                                unsigned char* __restrict__ selb) {
    const int t = blockIdx.x * 256 + threadIdx.x;  // BATCH*HW/8 threads
    const float4 i0 = img4[2 * t];
    const float4 i1 = img4[2 * t + 1];
    const float4 m0 = mask4[2 * t];
    const float4 m1 = mask4[2 * t + 1];
    out4[2 * t] = i0;
    out4[2 * t + 1] = i1;
    const unsigned by = (m0.x < 0.5f ? 1u : 0u) | (m0.y < 0.5f ? 2u : 0u) |
                        (m0.z < 0.5f ? 4u : 0u) | (m0.w < 0.5f ? 8u : 0u) |
                        (m1.x < 0.5f ? 16u : 0u) | (m1.y < 0.5f ? 32u : 0u) |
                        (m1.z < 0.5f ? 64u : 0u) | (m1.w < 0.5f ? 128u : 0u);
    selb[t] = (unsigned char)by;
}

// In-LDS insertion sort of srt[s..e). Runs are same-bucket (avg <=1, max ~5
// whp); correctness holds for ANY length. Lanes own disjoint ranges.
__device__ __forceinline__ void sort_run(unsigned long long* __restrict__ srt,
                                         int s, int e) {
    for (int i = s + 1; i < e; ++i) {
        const unsigned long long key = srt[i];
        int j = i - 1;
        while (j >= s && srt[j] > key) {
            srt[j + 1] = srt[j];
            --j;
        }
        srt[j + 1] = key;
    }
}

// ---------------------------------------------------------------------------
// Gather + LDS counting sort + epilogue (R8 rework).
//  - selection comes from the L2-resident selbit array (no mask gather)
//  - img is gathered ONLY for selected pixels, in arc order, into vlds
//  - key = prand_bits(32) << 16 | compact_index j (j ascending == pixel
//    ascending among selected -> identical stable tie-break, verified R4/R7)
//  - epilogue: out[dstpix[r]] = vlds[srt[r].low16] -- the rank->pixel random
//    access is an LDS read; both global ops stay in arc-contiguous order
//  - cleanup: deterministic per-lane insertion sort of each bucket run
//    (starts kept in registers from the prefix scan, ends from post-pass-B
//    cursors) -- replaces the multi-round odd-even fixpoint (R7)
// Returns k; if k > CAP nothing past pass A ran (caller defers to overflow).
// ---------------------------------------------------------------------------
template <int CAP>
__device__ int gather_count_sort(
    int b, int d, int lane,
    const float* __restrict__ img, const unsigned char* __restrict__ selb,
    const float* __restrict__ prand, float* __restrict__ out,
    const unsigned short* __restrict__ ring_pix, int n,
    unsigned long long* __restrict__ srt, unsigned* __restrict__ hist,
    unsigned short* __restrict__ dstpix, float* __restrict__ vlds) {
    const float* imgb = img + (size_t)b * HW;
    const unsigned char* sbb = selb + (size_t)b * HWB;
    const float* prb = prand + ((size_t)b * NUM_ROWS + d) * NUM_COLS;
    float* outb = out + (size_t)b * HW;
    const unsigned long long ltmask = (1ull << lane) - 1ull;
    const unsigned short* rp = ring_pix + d * NUM_COLS;

    // zero histogram (wave-private region)
#pragma unroll
    for (int t = 0; t < WPL; ++t) hist[t * 64 + lane] = 0;

    // Batched loads: ring_pix, selbit bytes, prand (all L2-hot or coalesced).
    int p[MAXC];
    unsigned char sb[MAXC];
    unsigned kb[MAXC];
#pragma unroll
    for (int c = 0; c < MAXC; ++c) p[c] = rp[min(c * 64 + lane, n - 1)];
#pragma unroll
    for (int c = 0; c < MAXC; ++c) sb[c] = sbb[p[c] >> 3];
#pragma unroll
    for (int c = 0; c < MAXC; ++c) kb[c] = __float_as_uint(prb[min(c * 64 + lane, n - 1)]);

    // selection bitmask per chunk (sb dies here -> frees VGPRs)
    unsigned selm = 0;
#pragma unroll
    for (int c = 0; c < MAXC; ++c) {
        const int i = c * 64 + lane;
        if ((i < n) && ((sb[c] >> (p[c] & 7)) & 1)) selm |= 1u << c;
    }

    // Selected-only img gather in arc order; issued early so its latency
    // hides under pass A + the prefix scan. Values land in vlds at pass B.
    float v[MAXC];
#pragma unroll
    for (int c = 0; c < MAXC; ++c)
        if ((selm >> c) & 1) v[c] = imgb[p[c]];

    lds_fence();  // hist zeroing ordered before atomics

    // Pass A: compact index via ballot (-> dstpix) + bucket histogram.
    int base = 0;
#pragma unroll
    for (int c = 0; c < MAXC; ++c) {
        const bool sel = (selm >> c) & 1;
        const unsigned long long ball = __ballot(sel);
        if (sel) {
            const int j = base + __popcll(ball & ltmask);
            if (j < CAP) dstpix[j] = (unsigned short)p[c];
            const int bk = (int)(__uint_as_float(kb[c]) * (float)NBUCK);
            atomicAdd(&hist[bk >> 1], 1u << ((bk & 1) * 16));
        }
        base += __popcll(ball);
    }
    const int base_static = base;
    // Dynamic tail (defensive; only if some ring has n > 64*MAXC).
    for (int c0 = MAXC * 64; c0 < n; c0 += 64) {
        const int i = c0 + lane;
        bool sel = false;
        int pp = 0;
        unsigned kk = 0;
        if (i < n) {
            pp = rp[i];
            kk = __float_as_uint(prb[i]);
            sel = (sbb[pp >> 3] >> (pp & 7)) & 1;
        }
        const unsigned long long ball = __ballot(sel);
        if (sel) {
            const int j = base + __popcll(ball & ltmask);
            if (j < CAP) {
                dstpix[j] = (unsigned short)pp;
                vlds[j] = imgb[pp];
            }
            const int bk = (int)(__uint_as_float(kk) * (float)NBUCK);
            atomicAdd(&hist[bk >> 1], 1u << ((bk & 1) * 16));
        }
        base += __popcll(ball);
    }
    const int k = base;
    if (k > CAP) return k;  // deep binomial tail: caller defers
    if (k == 0) return 0;

    lds_fence();  // histogram visible

    // Exclusive prefix over NBUCK buckets (packed halfword pairs). Keep the
    // per-lane bucket STARTS in registers (st[]) for the cleanup pass.
    unsigned neww[WPL];
    unsigned run = 0;
#pragma unroll
    for (int t = 0; t < WPL; ++t) {
        const unsigned w = hist[lane * WPL + t];
        const unsigned c0 = w & 0xffffu;
        neww[t] = run | ((run + c0) << 16);
        run += c0 + (w >> 16);
    }
    const unsigned own = run;
#pragma unroll
    for (int off = 1; off < 64; off <<= 1) {
        const unsigned o = __shfl_up(run, off, 64);
        if (lane >= off) run += o;
    }
    const unsigned bx = run - own;
    const unsigned bxp = bx | (bx << 16);
    unsigned st[WPL];
#pragma unroll
    for (int t = 0; t < WPL; ++t) {
        st[t] = neww[t] + bxp;
        hist[lane * WPL + t] = st[t];
    }

    lds_fence();  // cursors visible

    // Pass B: atomic-cursor scatter of keys + vlds fill (ballots replay
    // pass A exactly, so j is identical).
    int jb = 0;
#pragma unroll
    for (int c = 0; c < MAXC; ++c) {
        const bool sel = (selm >> c) & 1;
        const unsigned long long ball = __ballot(sel);
        if (sel) {
            const int j = jb + __popcll(ball & ltmask);
            const int bk = (int)(__uint_as_float(kb[c]) * (float)NBUCK);
            const unsigned sh = (unsigned)((bk & 1) * 16);
            const unsigned old = atomicAdd(&hist[bk >> 1], 1u << sh);
            const int pos = (int)((old >> sh) & 0xffffu);
            srt[pos] = ((unsigned long long)kb[c] << 16) | (unsigned)j;
            vlds[j] = v[c];
        }
        jb += __popcll(ball);
    }
    int tb = base_static;
    for (int c0 = MAXC * 64; c0 < n; c0 += 64) {  // tail replay (cold)
        const int i = c0 + lane;
        bool sel = false;
        int pp = 0;
        unsigned kk = 0;
        if (i < n) {
            pp = rp[i];
            kk = __float_as_uint(prb[i]);
            sel = (sbb[pp >> 3] >> (pp & 7)) & 1;
        }
        const unsigned long long ball = __ballot(sel);
        if (sel) {
            const int j = tb + __popcll(ball & ltmask);
            const int bk = (int)(__uint_as_float(kk) * (float)NBUCK);
            const unsigned sh = (unsigned)((bk & 1) * 16);
            const unsigned old = atomicAdd(&hist[bk >> 1], 1u << sh);
            const int pos = (int)((old >> sh) & 0xffffu);
            srt[pos] = ((unsigned long long)kk << 16) | (unsigned)j;
            // vlds for tail was filled in pass A
        }
        tb += __popcll(ball);
    }

    lds_fence();  // scatter complete

    // Cleanup: each lane insertion-sorts its 8 buckets' runs. Starts from
    // st[] (registers), ends from post-pass-B cursors in hist. Single pass,
    // no fixpoint, no extra fences.
#pragma unroll
    for (int t = 0; t < WPL; ++t) {
        const unsigned wend = hist[lane * WPL + t];
        const unsigned ws0 = st[t];
        sort_run(srt, (int)(ws0 & 0xffffu), (int)(wend & 0xffffu));
        sort_run(srt, (int)(ws0 >> 16), (int)(wend >> 16));
    }

    lds_fence();  // sorted keys visible

    // Epilogue: rank r -> value vlds[j(srt[r])] -> out at the r-th occupied
    // slot (dstpix[r], arc order -> coalesced-ish stores). Unrolled so all
    // independent LDS reads issue together.
    const unsigned short* s16 = (const unsigned short*)srt;
#pragma unroll
    for (int e = 0; e < CAP / 64; ++e) {
        const int r = e * 64 + lane;
        if (r < k) {
            const int j = s16[4 * r];  // low 16 bits of key = compact index
            const float val = vlds[j];
            outb[dstpix[r]] = val;
        }
    }
    return k;
}

// ---------------------------------------------------------------------------
// Main: one WAVE per (batch, ring); 4 waves/block; XCD-swizzled (16 whole
// images per XCD). No block barriers — waves fully independent.
// LDS: 4 x (4K srt + 1K hist + 1K dstpix + 2K vlds) = 32 KB -> 5 blk/CU.
// ---------------------------------------------------------------------------
__global__ __launch_bounds__(256) void radial_shuffle(
    const float* __restrict__ img, const unsigned char* __restrict__ selb,
    const float* __restrict__ prand, float* __restrict__ out,
    const unsigned short* __restrict__ ring_pix, const int* __restrict__ ring_cnt,
    int* __restrict__ ovf_cnt, int* __restrict__ ovf_list) {
    const int tid = threadIdx.x;
    const int wid = tid >> 6;
    const int lane = tid & 63;
    const int xcd = blockIdx.x & 7;
    const int g = (blockIdx.x >> 3) * 4 + wid;  // 0..2543 within XCD
    const int b = xcd * (BATCH / 8) + g / NUM_ROWS;
    const int d = g % NUM_ROWS;
    const int n = ring_cnt[d];

    __shared__ unsigned long long srt_s[4][512];  // 16 KB
    __shared__ unsigned hist_s[4][NHWORDS];       // 4 KB
    __shared__ unsigned short dp_s[4][512];       // 4 KB
    __shared__ float vl_s[4][512];                // 8 KB

    const int k = gather_count_sort<512>(b, d, lane, img, selb, prand, out,
                                         ring_pix, n, srt_s[wid], hist_s[wid],
                                         dp_s[wid], vl_s[wid]);

    if (k > 512) {
        // deep binomial tail: defer to overflow kernel
        if (lane == 0) {
            const int idx = atomicAdd(ovf_cnt, 1);
            if (idx < OVF_CAP) ovf_list[idx] = b * NUM_ROWS + d;
        }
    }
}

// Cold path: rings with k > 512 (capacity 1024 >= any ring).
__global__ __launch_bounds__(64) void overflow_sort(
    const float* __restrict__ img, const unsigned char* __restrict__ selb,
    const float* __restrict__ prand, float* __restrict__ out,
    const unsigned short* __restrict__ ring_pix, const int* __restrict__ ring_cnt,
    const int* __restrict__ ovf_cnt, const int* __restrict__ ovf_list) {
    __shared__ unsigned long long srt[1024];   // 8 KB
    __shared__ unsigned hist[NHWORDS];         // 1 KB
    __shared__ unsigned short dstpix[1024];    // 2 KB
    __shared__ float vlds[1024];               // 4 KB
    const int m = min(*ovf_cnt, OVF_CAP);
    const int lane = threadIdx.x;
    for (int t = blockIdx.x; t < m; t += gridDim.x) {
        const int bd = ovf_list[t];
        const int b = bd / NUM_ROWS;
        const int d = bd % NUM_ROWS;
        gather_count_sort<1024>(b, d, lane, img, selb, prand, out, ring_pix,
                                ring_cnt[d], srt, hist, dstpix, vlds);
        __syncthreads();  // before LDS reuse (single wave: cheap)
    }
}

extern "C" void kernel_launch(void* const* d_in, const int* in_sizes, int n_in,
                              void* d_out, int out_size, void* d_ws, size_t ws_size,
                              hipStream_t stream) {
    const float* img   = (const float*)d_in[0];  // (128,224,224,1) f32
    const float* mask  = (const float*)d_in[1];  // (128,224,224)   f32
    const float* prand = (const float*)d_in[2];  // (128,159,1024)  f32
    float* out = (float*)d_out;                  // (128,224,224,1) f32

    // Workspace layout (~1.15 MB total):
    unsigned short* ring_pix = (unsigned short*)d_ws;  // 159*1024 u16
    int* ring_cnt = (int*)((char*)d_ws + NUM_ROWS * NUM_COLS * sizeof(unsigned short));
    int* ovf_cnt  = ring_cnt + NUM_ROWS;
    int* ovf_list = ovf_cnt + 1;
    unsigned char* selb = (unsigned char*)(ovf_list + OVF_CAP);  // BATCH*HWB bytes

    hipLaunchKernelGGL(build_rings, dim3(NUM_ROWS), dim3(256), 0, stream,
                       ring_pix, ring_cnt, ovf_cnt);
    hipLaunchKernelGGL(copy_sel, dim3(BATCH * HW / 8 / 256), dim3(256), 0, stream,
                       (const float4*)img, (const float4*)mask, (float4*)out, selb);
    hipLaunchKernelGGL(radial_shuffle, dim3(BATCH * NUM_ROWS / 4), dim3(256), 0,
                       stream, img, selb, prand, out, ring_pix, ring_cnt,
                       ovf_cnt, ovf_list);
    hipLaunchKernelGGL(overflow_sort, dim3(32), dim3(64), 0, stream,
                       img, selb, prand, out, ring_pix, ring_cnt,
                       ovf_cnt, ovf_list);
}

// Round 3
// 198.406 us; speedup vs baseline: 1.2609x; 1.0133x over previous
//
#include <hip/hip_runtime.h>

#define IMG_H 224
#define IMG_W 224
#define HW (IMG_H * IMG_W)   // 50176 (divisible by 8)
#define HWB (HW / 8)         // 6272 selbit bytes per image
#define NUM_ROWS 159
#define NUM_COLS 1024
#define BATCH 128
#define OVF_CAP 4096
#define MAXC 12              // static chunks cover 768 >= max ring (~703); tail defensive
#define NBUCK 512            // counting-sort buckets; bucket = floor(val*512), exact & monotone
#define NHWORDS (NBUCK / 2)  // u32 words, 2 packed u16 counters each
#define WPL (NHWORDS / 64)   // 4 hist words (8 buckets) owned per lane

// Exact integer sqrt (v <= ~25k here, f32 sqrt + fixup loops).
__device__ __forceinline__ int isqrt_i(int v) {
    int u = (int)sqrtf((float)v);
    while (u > 0 && u * u > v) --u;
    while ((u + 1) * (u + 1) <= v) ++u;
    return u;
}

// Compiler + wave-order fence for wave-private LDS (DS pipe is in-order per
// wave; the asm stops compiler reordering and drains lgkm before reuse).
__device__ __forceinline__ void lds_fence() {
    asm volatile("s_waitcnt lgkmcnt(0)" ::: "memory");
}

// ---------------------------------------------------------------------------
// Fused pre-pass (R9): blocks [0,159) build the ring tables (verified R3-R5
// analytic form); blocks [159,...) do the coalesced out=img copy + selbit
// pack (R8). Independent work fused to save one launch gap.
// ---------------------------------------------------------------------------
__global__ __launch_bounds__(256) void pre_pass(
    const float4* __restrict__ img4, const float4* __restrict__ mask4,
    float4* __restrict__ out4, unsigned char* __restrict__ selb,
    unsigned short* __restrict__ ring_pix, int* __restrict__ ring_cnt,
    int* __restrict__ ovf_cnt) {
    const int bid = blockIdx.x;
    const int tid = threadIdx.x;
    __shared__ int scnt[256];

    if (bid < NUM_ROWS) {
        // ---- ring build: round(sqrt(dx^2+dy^2)) == d
        //      <=> Araw <= dx^2+dy^2 <= d^2+d, Araw = (d==0 ? 0 : d^2-d+1)
        const int d = bid;
        if (d == 0 && tid == 0) ovf_cnt[0] = 0;
        int cnt = 0;
        int x0l = 0, x1l = -1, x0r = 0, x1r = -1;
        if (tid < IMG_H) {
            const int dy = tid - 112;
            const int Araw = (d == 0) ? 0 : (d * d - d + 1);
            int A = Araw - dy * dy;
            if (A < 0) A = 0;
            const int B = d * d + d - dy * dy;
            if (B >= 0) {
                const int hi = isqrt_i(B);
                int lo = isqrt_i(A);
                if (lo * lo < A) ++lo;
                if (lo <= hi) {
                    if (lo == 0) {
                        x0l = 112 - min(hi, 112);
                        x1l = 112 + min(hi, 111);
                    } else {
                        x0l = 112 - min(hi, 112);
                        x1l = 112 - lo;
                        x0r = 112 + lo;
                        x1r = 112 + min(hi, 111);
                    }
                    cnt = max(0, x1l - x0l + 1) + max(0, x1r - x0r + 1);
                }
            }
        }
        scnt[tid] = cnt;
        __syncthreads();
        for (int off = 1; off < 256; off <<= 1) {
            const int mine = scnt[tid];
            const int add = (tid >= off) ? scnt[tid - off] : 0;
            __syncthreads();
            scnt[tid] = mine + add;
            __syncthreads();
        }
        if (tid < IMG_H && cnt > 0) {
            int j = d * NUM_COLS + (scnt[tid] - cnt);
            const int rowbase = tid * IMG_W;
            for (int x = x0l; x <= x1l; ++x) ring_pix[j++] = (unsigned short)(rowbase + x);
            for (int x = x0r; x <= x1r; ++x) ring_pix[j++] = (unsigned short)(rowbase + x);
        }
        if (tid == 255) ring_cnt[d] = scnt[255];
    } else {
        // ---- coalesced copy + selbit pack (8 px/thread)
        const int t = (bid - NUM_ROWS) * 256 + tid;  // < BATCH*HW/8
        const float4 i0 = img4[2 * t];
        const float4 i1 = img4[2 * t + 1];
        const float4 m0 = mask4[2 * t];
        const float4 m1 = mask4[2 * t + 1];
        out4[2 * t] = i0;
        out4[2 * t + 1] = i1;
        const unsigned by = (m0.x < 0.5f ? 1u : 0u) | (m0.y < 0.5f ? 2u : 0u) |
                            (m0.z < 0.5f ? 4u : 0u) | (m0.w < 0.5f ? 8u : 0u) |
                            (m1.x < 0.5f ? 16u : 0u) | (m1.y < 0.5f ? 32u : 0u) |
                            (m1.z < 0.5f ? 64u : 0u) | (m1.w < 0.5f ? 128u : 0u);
        selb[t] = (unsigned char)by;
    }
}

// In-LDS insertion sort of the (key32, j16) pair arrays over [s, e).
// Order identical to u64 (key<<16|j) compare since j < 2^16. Runs are
// same-bucket (avg <=1); correctness holds for ANY length.
__device__ __forceinline__ void sort_run2(unsigned* __restrict__ k32,
                                          unsigned short* __restrict__ j16,
                                          int s, int e) {
    for (int i = s + 1; i < e; ++i) {
        const unsigned key = k32[i];
        const unsigned short jj = j16[i];
        int q = i - 1;
        while (q >= s && (k32[q] > key || (k32[q] == key && j16[q] > jj))) {
            k32[q + 1] = k32[q];
            j16[q + 1] = j16[q];
            --q;
        }
        k32[q + 1] = key;
        j16[q + 1] = jj;
    }
}

// ---------------------------------------------------------------------------
// Gather + LDS counting sort + epilogue (R9 rework).
// vs R8: (1) per-chunk wave-uniform guards `if (c*64 < n)` skip ~55% of all
// chunk VALU/VMEM (avg ring needs 5.4 of 12 chunks); (2) compact index jc[]
// register-cached from pass A -> pass B needs no ballot replay; (3) dstpix
// deleted: dstpix[r] == p of compact index r, so the epilogue is
// out[p[c]] = vlds[srtj[jc[c]]] from registers; (4) key split into
// srt32+srtj16 -> 24 KB LDS/block -> 6 blocks/CU (+20% resident waves).
// Key order = (prand_bits, j) with j ascending == pixel ascending among
// selected -> identical stable tie-break as jax argsort (verified R4/R7/R8).
// Returns k; if k > CAP caller defers to the overflow kernel.
// ---------------------------------------------------------------------------
template <int CAP>
__device__ int gather_count_sort(
    int b, int d, int lane, int n,
    const float* __restrict__ img, const unsigned char* __restrict__ selb,
    const float* __restrict__ prand, float* __restrict__ out,
    const unsigned short* __restrict__ ring_pix,
    unsigned* __restrict__ srt32, unsigned short* __restrict__ srtj,
    unsigned* __restrict__ hist, float* __restrict__ vlds) {
    const float* imgb = img + (size_t)b * HW;
    const unsigned char* sbb = selb + (size_t)b * HWB;
    const float* prb = prand + ((size_t)b * NUM_ROWS + d) * NUM_COLS;
    float* outb = out + (size_t)b * HW;
    const unsigned long long ltmask = (1ull << lane) - 1ull;
    const unsigned short* rp = ring_pix + d * NUM_COLS;

    // zero histogram (wave-private region)
#pragma unroll
    for (int t = 0; t < WPL; ++t) hist[t * 64 + lane] = 0;

    // Batched guarded loads (all L2-hot or coalesced). Guards are scalar
    // branches (n is wave-uniform via readfirstlane in the caller).
    int p[MAXC];
    unsigned char sb[MAXC];
    unsigned kb[MAXC];
#pragma unroll
    for (int c = 0; c < MAXC; ++c)
        if (c * 64 < n) p[c] = rp[min(c * 64 + lane, n - 1)];
#pragma unroll
    for (int c = 0; c < MAXC; ++c)
        if (c * 64 < n) sb[c] = sbb[p[c] >> 3];
#pragma unroll
    for (int c = 0; c < MAXC; ++c)
        if (c * 64 < n) kb[c] = __float_as_uint(prb[c * 64 + lane]);  // i<768<=1024: always valid

    unsigned selm = 0;
#pragma unroll
    for (int c = 0; c < MAXC; ++c)
        if (c * 64 < n) {
            if ((c * 64 + lane) < n && ((sb[c] >> (p[c] & 7)) & 1)) selm |= 1u << c;
        }

    // Selected-only img gather in arc order; issued early so its latency
    // hides under pass A + the prefix scan. Values land in vlds at pass B.
    float v[MAXC];
#pragma unroll
    for (int c = 0; c < MAXC; ++c)
        if (c * 64 < n) {
            if ((selm >> c) & 1) v[c] = imgb[p[c]];
        }

    lds_fence();  // hist zeroing ordered before atomics

    // Pass A: compact index via ballot (cached in jc[]) + bucket histogram.
    int jc[MAXC];
    int base = 0;
#pragma unroll
    for (int c = 0; c < MAXC; ++c)
        if (c * 64 < n) {
            const bool sel = (selm >> c) & 1;
            const unsigned long long ball = __ballot(sel);
            if (sel) {
                jc[c] = base + __popcll(ball & ltmask);
                const int bk = (int)(__uint_as_float(kb[c]) * (float)NBUCK);
                atomicAdd(&hist[bk >> 1], 1u << ((bk & 1) * 16));
            }
            base += __popcll(ball);
        }
    const int base_static = base;
    // Dynamic tail (defensive; only if some ring has n > 64*MAXC).
    for (int c0 = MAXC * 64; c0 < n; c0 += 64) {
        const int i = c0 + lane;
        bool sel = false;
        int pp = 0;
        unsigned kk = 0;
        if (i < n) {
            pp = rp[i];
            kk = __float_as_uint(prb[i]);
            sel = (sbb[pp >> 3] >> (pp & 7)) & 1;
        }
        const unsigned long long ball = __ballot(sel);
        if (sel) {
            const int j = base + __popcll(ball & ltmask);
            if (j < CAP) vlds[j] = imgb[pp];
            const int bk = (int)(__uint_as_float(kk) * (float)NBUCK);
            atomicAdd(&hist[bk >> 1], 1u << ((bk & 1) * 16));
        }
        base += __popcll(ball);
    }
    const int k = base;
    if (k > CAP) return k;  // deep binomial tail: caller defers
    if (k == 0) return 0;

    lds_fence();  // histogram visible

    // Exclusive prefix over NBUCK buckets (packed halfword pairs). Bucket
    // STARTS kept in registers (st[]) for the cleanup pass.
    unsigned neww[WPL];
    unsigned run = 0;
#pragma unroll
    for (int t = 0; t < WPL; ++t) {
        const unsigned w = hist[lane * WPL + t];
        const unsigned c0 = w & 0xffffu;
        neww[t] = run | ((run + c0) << 16);
        run += c0 + (w >> 16);
    }
    const unsigned own = run;
#pragma unroll
    for (int off = 1; off < 64; off <<= 1) {
        const unsigned o = __shfl_up(run, off, 64);
        if (lane >= off) run += o;
    }
    const unsigned bx = run - own;
    const unsigned bxp = bx | (bx << 16);
    unsigned st[WPL];
#pragma unroll
    for (int t = 0; t < WPL; ++t) {
        st[t] = neww[t] + bxp;
        hist[lane * WPL + t] = st[t];
    }

    lds_fence();  // cursors visible

    // Pass B: atomic-cursor scatter of (key, j) + vlds fill. No ballot
    // replay: j comes from jc[].
#pragma unroll
    for (int c = 0; c < MAXC; ++c)
        if (c * 64 < n) {
            if ((selm >> c) & 1) {
                const int bk = (int)(__uint_as_float(kb[c]) * (float)NBUCK);
                const unsigned sh = (unsigned)((bk & 1) * 16);
                const unsigned old = atomicAdd(&hist[bk >> 1], 1u << sh);
                const int pos = (int)((old >> sh) & 0xffffu);
                srt32[pos] = kb[c];
                srtj[pos] = (unsigned short)jc[c];
                vlds[jc[c]] = v[c];
            }
        }
    int tb = base_static;
    for (int c0 = MAXC * 64; c0 < n; c0 += 64) {  // tail replay (cold)
        const int i = c0 + lane;
        bool sel = false;
        int pp = 0;
        unsigned kk = 0;
        if (i < n) {
            pp = rp[i];
            kk = __float_as_uint(prb[i]);
            sel = (sbb[pp >> 3] >> (pp & 7)) & 1;
        }
        const unsigned long long ball = __ballot(sel);
        if (sel) {
            const int j = tb + __popcll(ball & ltmask);
            const int bk = (int)(__uint_as_float(kk) * (float)NBUCK);
            const unsigned sh = (unsigned)((bk & 1) * 16);
            const unsigned old = atomicAdd(&hist[bk >> 1], 1u << sh);
            const int pos = (int)((old >> sh) & 0xffffu);
            srt32[pos] = kk;
            srtj[pos] = (unsigned short)j;
            // vlds for tail was filled in pass A
        }
        tb += __popcll(ball);
    }

    lds_fence();  // scatter complete

    // Cleanup: each lane insertion-sorts its 8 buckets' runs. Starts from
    // st[] (registers), ends from post-pass-B cursors in hist.
#pragma unroll
    for (int t = 0; t < WPL; ++t) {
        const unsigned wend = hist[lane * WPL + t];
        const unsigned ws0 = st[t];
        sort_run2(srt32, srtj, (int)(ws0 & 0xffffu), (int)(wend & 0xffffu));
        sort_run2(srt32, srtj, (int)(ws0 >> 16), (int)(wend >> 16));
    }

    lds_fence();  // sorted keys visible

    // Epilogue: compact slot q receives the value of the rank-q element:
    // out[p_q] = vlds[srtj[q]]. Each lane handles its own selected elements
    // (q = jc[c], pixel = p[c]) -> arc-order coalesced stores, no dstpix.
#pragma unroll
    for (int c = 0; c < MAXC; ++c)
        if (c * 64 < n) {
            if ((selm >> c) & 1) {
                const int jp = srtj[jc[c]];
                outb[p[c]] = vlds[jp];
            }
        }
    tb = base_static;
    for (int c0 = MAXC * 64; c0 < n; c0 += 64) {  // tail epilogue (cold)
        const int i = c0 + lane;
        bool sel = false;
        int pp = 0;
        if (i < n) {
            pp = rp[i];
            sel = (sbb[pp >> 3] >> (pp & 7)) & 1;
        }
        const unsigned long long ball = __ballot(sel);
        if (sel) {
            const int j = tb + __popcll(ball & ltmask);
            const int jp = srtj[j];
            outb[pp] = vlds[jp];
        }
        tb += __popcll(ball);
    }
    return k;
}

// ---------------------------------------------------------------------------
// Main: one WAVE per (batch, ring); 4 waves/block; XCD-swizzled (16 whole
// images per XCD). No block barriers — waves fully independent.
// LDS: 4 x (2K srt32 + 1K srtj + 1K hist + 2K vlds) = 24 KB -> 6 blk/CU.
// ---------------------------------------------------------------------------
__global__ __launch_bounds__(256, 6) void radial_shuffle(
    const float* __restrict__ img, const unsigned char* __restrict__ selb,
    const float* __restrict__ prand, float* __restrict__ out,
    const unsigned short* __restrict__ ring_pix, const int* __restrict__ ring_cnt,
    int* __restrict__ ovf_cnt, int* __restrict__ ovf_list) {
    const int tid = threadIdx.x;
    const int wid = tid >> 6;
    const int lane = tid & 63;
    const int xcd = blockIdx.x & 7;
    const int g = (blockIdx.x >> 3) * 4 + wid;  // 0..2543 within XCD
    const int b = xcd * (BATCH / 8) + g / NUM_ROWS;
    const int d = g % NUM_ROWS;
    const int n = __builtin_amdgcn_readfirstlane(ring_cnt[d]);  // scalar -> uniform branches

    __shared__ unsigned srt32_s[4][512];       // 8 KB
    __shared__ unsigned short srtj_s[4][512];  // 4 KB
    __shared__ unsigned hist_s[4][NHWORDS];    // 4 KB
    __shared__ float vl_s[4][512];             // 8 KB

    const int k = gather_count_sort<512>(b, d, lane, n, img, selb, prand, out,
                                         ring_pix, srt32_s[wid], srtj_s[wid],
                                         hist_s[wid], vl_s[wid]);

    if (k > 512) {
        // deep binomial tail: defer to overflow kernel
        if (lane == 0) {
            const int idx = atomicAdd(ovf_cnt, 1);
            if (idx < OVF_CAP) ovf_list[idx] = b * NUM_ROWS + d;
        }
    }
}

// Cold path: rings with k > 512 (capacity 1024 >= any ring).
__global__ __launch_bounds__(64) void overflow_sort(
    const float* __restrict__ img, const unsigned char* __restrict__ selb,
    const float* __restrict__ prand, float* __restrict__ out,
    const unsigned short* __restrict__ ring_pix, const int* __restrict__ ring_cnt,
    const int* __restrict__ ovf_cnt, const int* __restrict__ ovf_list) {
    __shared__ unsigned srt32[1024];       // 4 KB
    __shared__ unsigned short srtj[1024];  // 2 KB
    __shared__ unsigned hist[NHWORDS];     // 1 KB
    __shared__ float vlds[1024];           // 4 KB
    const int m = min(*ovf_cnt, OVF_CAP);
    const int lane = threadIdx.x;
    for (int t = blockIdx.x; t < m; t += gridDim.x) {
        const int bd = ovf_list[t];
        const int b = bd / NUM_ROWS;
        const int d = bd % NUM_ROWS;
        const int n = __builtin_amdgcn_readfirstlane(ring_cnt[d]);
        gather_count_sort<1024>(b, d, lane, n, img, selb, prand, out, ring_pix,
                                srt32, srtj, hist, vlds);
        __syncthreads();  // before LDS reuse (single wave: cheap)
    }
}

extern "C" void kernel_launch(void* const* d_in, const int* in_sizes, int n_in,
                              void* d_out, int out_size, void* d_ws, size_t ws_size,
                              hipStream_t stream) {
    const float* img   = (const float*)d_in[0];  // (128,224,224,1) f32
    const float* mask  = (const float*)d_in[1];  // (128,224,224)   f32
    const float* prand = (const float*)d_in[2];  // (128,159,1024)  f32
    float* out = (float*)d_out;                  // (128,224,224,1) f32

    // Workspace layout (~1.15 MB total):
    unsigned short* ring_pix = (unsigned short*)d_ws;  // 159*1024 u16
    int* ring_cnt = (int*)((char*)d_ws + NUM_ROWS * NUM_COLS * sizeof(unsigned short));
    int* ovf_cnt  = ring_cnt + NUM_ROWS;
    int* ovf_list = ovf_cnt + 1;
    unsigned char* selb = (unsigned char*)(ovf_list + OVF_CAP);  // BATCH*HWB bytes

    hipLaunchKernelGGL(pre_pass, dim3(NUM_ROWS + BATCH * HW / 8 / 256), dim3(256),
                       0, stream, (const float4*)img, (const float4*)mask,
                       (float4*)out, selb, ring_pix, ring_cnt, ovf_cnt);
    hipLaunchKernelGGL(radial_shuffle, dim3(BATCH * NUM_ROWS / 4), dim3(256), 0,
                       stream, img, selb, prand, out, ring_pix, ring_cnt,
                       ovf_cnt, ovf_list);
    hipLaunchKernelGGL(overflow_sort, dim3(32), dim3(64), 0, stream,
                       img, selb, prand, out, ring_pix, ring_cnt,
                       ovf_cnt, ovf_list);
}